// Round 7
// baseline (639.286 us; speedup 1.0000x reference)
//
#include <hip/hip_runtime.h>
#include <math.h>

#define N 8192
#define H 128
#define BB 100
#define KK 5
#define MAXN 256
#define TD_MAXF 10000.0f

// ws float-offset layout constants (single-base addressing for the gather)
#define OFF_WHALLV ((size_t)N * H)          // versioned whall rows
#define OFF_ZVER (OFF_WHALLV + 2 * BB * H)  // versioned z rows

// ---------------------------------------------------------------------------
// K1: fused build, by block range (raw weights -- no transposes needed):
//   [0, N/2)             : whall = z0 @ Wh.T + Wh_b, 2 rows per block
//   [N/2, N/2+2*BB)      : nbr list build + DAG resolve for list l
//   [N/2+2*BB, +N/256)   : dbase (per-node omega dots from z0)
__global__ __launch_bounds__(256) void build_kernel(
    const float* __restrict__ z0, const float* __restrict__ Wh,
    const float* __restrict__ Wh_b, float* __restrict__ whall,
    const int* __restrict__ u_, const int* __restrict__ v_,
    const float* __restrict__ A, const float* __restrict__ S,
    const float* __restrict__ om0, const float* __restrict__ om1,
    float* __restrict__ dvec0, int* __restrict__ cnt, int* __restrict__ nidx,
    float* __restrict__ nes, float* __restrict__ qsum, int* __restrict__ woff,
    int* __restrict__ zsrc, unsigned* __restrict__ need) {
  const int blk = blockIdx.x;
  const int tid = threadIdx.x;
  __shared__ float zr2[2][H];
  __shared__ int cnts[256];
  __shared__ int excl[257];
  __shared__ float ssum[256];
  __shared__ int nidxL[MAXN];
  __shared__ int uL[BB], vL[BB];

  if (blk < N / 2) {
    // ---- whall: raw Wh rows (thread-contiguous, L2-hot) ------------------
    int r = tid >> 7, d = tid & (H - 1);
    int row = blk * 2 + r;
    zr2[r][d] = z0[(size_t)row * H + d];
    __syncthreads();
    float acc = Wh_b[d];
    const float4* w4 = (const float4*)(Wh + (size_t)d * H);
    const float4* z4 = (const float4*)zr2[r];
#pragma unroll 8
    for (int k4 = 0; k4 < H / 4; ++k4) {
      float4 wv = w4[k4];
      float4 zv = z4[k4];
      acc += zv.x * wv.x + zv.y * wv.y + zv.z * wv.z + zv.w * wv.w;
    }
    whall[(size_t)row * H + d] = acc;
    return;
  }
  if (blk >= N / 2 + 2 * BB) {
    // ---- dbase: dvec0 = [dL0|dR0|dL1|dR1] ---------------------------------
    int j = (blk - N / 2 - 2 * BB) * 256 + tid;
    const float4* zr = (const float4*)(z0 + (size_t)j * H);
    const float4* o0 = (const float4*)om0;
    const float4* o1 = (const float4*)om1;
    float a0 = 0, b0 = 0, a1 = 0, b1 = 0;
    for (int k = 0; k < H / 4; ++k) {
      float4 zv = zr[k];
      float4 l0 = o0[k], r0 = o0[k + H / 4];
      float4 l1 = o1[k], r1 = o1[k + H / 4];
      a0 += zv.x * l0.x + zv.y * l0.y + zv.z * l0.z + zv.w * l0.w;
      b0 += zv.x * r0.x + zv.y * r0.y + zv.z * r0.z + zv.w * r0.w;
      a1 += zv.x * l1.x + zv.y * l1.y + zv.z * l1.z + zv.w * l1.w;
      b1 += zv.x * r1.x + zv.y * r1.y + zv.z * r1.z + zv.w * r1.w;
    }
    dvec0[0 * N + j] = a0;
    dvec0[1 * N + j] = b0;
    dvec0[2 * N + j] = a1;
    dvec0[3 * N + j] = b1;
    return;
  }

  // ---- nbr + dag for list l = 2*b + r (r=0 -> v_b, r=1 -> u_b) -----------
  const int l = blk - N / 2;
  const int b = l >> 1, r = l & 1;
  const int node = r ? u_[b] : v_[b];
  int c = 0;
  float local = 0.0f;
  unsigned hitmask = 0u;  // single-pass A: remember hits per iteration
  for (int it = 0; it < N / 256; ++it) {
    int j = it * 256 + tid;
    if (A[(size_t)node * N + j] > 0.0f) {
      hitmask |= (1u << it);
      ++c;
      local += expf(S[(size_t)node * N + j]);
    }
  }
  cnts[tid] = c;
  ssum[tid] = local;
  __syncthreads();
  if (tid == 0) {
    int s = 0;
    for (int i = 0; i < 256; ++i) { excl[i] = s; s += cnts[i]; }
    excl[256] = s;
  }
  __syncthreads();
  int p = excl[tid];
  for (int it = 0; it < N / 256; ++it) {
    if ((hitmask >> it) & 1u) {
      int j = it * 256 + tid;
      if (p < MAXN) {
        nidx[l * MAXN + p] = j;
        nidxL[p] = j;
        nes[l * MAXN + p] = expf(S[(size_t)node * N + j]);
      }
      ++p;
    }
  }
  if (tid < BB) {
    uL[tid] = u_[tid];
    vL[tid] = v_[tid];
  }
  __syncthreads();
  for (int s = 128; s > 0; s >>= 1) {
    if (tid < s) ssum[tid] += ssum[tid + s];
    __syncthreads();
  }
  const int cM = min(excl[256], MAXN);
  if (tid == 0) {
    cnt[l] = cM;
    qsum[l] = ssum[0];
  }
  for (int i = tid; i < cM; i += 256) {
    int n = nidxL[i];
    int a = -1, row = 0;
    for (int s = b - 1; s >= 0; --s) {
      if (vL[s] == n) { a = s; row = 1; break; }
      if (uL[s] == n) { a = s; row = 0; break; }
    }
    int off;
    if (a < 0) {
      off = n * H;
    } else {
      off = (int)OFF_WHALLV + (2 * a + row) * H;
      atomicOr(&need[b * 4 + (a >> 5)], 1u << (a & 31));
    }
    woff[l * MAXN + i] = off;
  }
  if (r == 0 && tid >= 254) {
    int which = tid - 254;  // 0 -> u_b, 1 -> v_b
    int nd = which ? vL[b] : uL[b];
    int a = -1, row = 0;
    for (int s = b - 1; s >= 0; --s) {
      if (vL[s] == nd) { a = s; row = 1; break; }
      if (uL[s] == nd) { a = s; row = 0; break; }
    }
    int sv = -1;
    if (a >= 0) {
      sv = 2 * a + row;
      atomicOr(&need[b * 4 + (a >> 5)], 1u << (a & 31));
    }
    zsrc[2 * b + which] = sv;
  }
}

// ---------------------------------------------------------------------------
// K2 fused: blocks [0,BB) = DAG-parallel step; blocks [BB,2BB) = lam for
// step blk-BB (polls the same done bits; needs only steps < b).
__global__ __launch_bounds__(1024) void fused_kernel(
    const int* __restrict__ u_, const int* __restrict__ v_,
    const int* __restrict__ et_, const int* __restrict__ neg_,
    const float* __restrict__ time_diff, const float* __restrict__ t_bar,
    const float* __restrict__ tt, const float* __restrict__ z0,
    const float* __restrict__ Wh, const float* __restrict__ Ws,
    const float* __restrict__ Wr, const float* __restrict__ om0_w,
    const float* __restrict__ om1_w, const float* __restrict__ Wh_b,
    const float* __restrict__ Ws_b, const float* __restrict__ Wr_b,
    const float* __restrict__ Wt_w, const float* __restrict__ Wt_b,
    const float* __restrict__ w_t, const float* __restrict__ alpha,
    const float* __restrict__ psi, const float* __restrict__ om0_b,
    const float* __restrict__ om1_b, const float* __restrict__ wsf,
    float* __restrict__ zver, float* __restrict__ whallv,
    float* __restrict__ dlog, const float* __restrict__ qsum_,
    const int* __restrict__ cnt_, const float* __restrict__ nes_,
    const int* __restrict__ woff_, const int* __restrict__ zsrc_,
    const float* __restrict__ dvec0, const unsigned* __restrict__ need,
    unsigned* done, float* __restrict__ out) {
  const int blk = blockIdx.x;
  const int t = threadIdx.x;
  // step-part LDS
  __shared__ float scratch[8][2][H];
  __shared__ float hsS[2][H];
  __shared__ float zrowS[2][H];
  __shared__ float zupdS[2][H];
  __shared__ float td2S[2][4];
  __shared__ int woffS[2][MAXN];
  __shared__ float nqS[2][MAXN];
  __shared__ int cntS[2];
  __shared__ int uvS[2];
  // lam-part LDS
  __shared__ float dR[N];  // 32 KB
  __shared__ int uS[BB], vS[BB];
  __shared__ float red[1024];
  __shared__ float suS, svS;

  if (blk < BB) {
    // =============================== STEP ================================
    const int b = blk;
    const int r = t >> 9;
    const int sub = (t >> 7) & 3;
    const int d = t & (H - 1);
    const int l = 2 * b + r;
    const int c = cnt_[l];
    const float iq = 1.0f / (qsum_[l] + 1e-7f);
    const int ks = t >> 7;
    const int k0 = ks * 16;

    // ---- pre-poll staging (LDS) ----
    if (t < 512) {
      int rr = t >> 8, i = t & 255;
      woffS[rr][i] = woff_[(2 * b + rr) * MAXN + i];
      nqS[rr][i] = nes_[(2 * b + rr) * MAXN + i];
    } else if (t < 520) {
      int i = t - 512;
      int cc = i & 3;
      float sd = (cc == 0) ? 50.0f : ((cc == 1) ? 7.0f : 15.0f);
      td2S[i >> 2][cc] = time_diff[b * 8 + i] / sd;
    } else if (t < 522) {
      cntS[t - 520] = cnt_[2 * b + (t - 520)];
    } else if (t == 522) {
      uvS[0] = u_[b];
    } else if (t == 523) {
      uvS[1] = v_[b];
    }
    // ---- pre-poll register prefetch from RAW weights (inputs: ready) ----
    float wsReg[16], wrReg[16], whReg[16];
    {
      const float4* ws4 = (const float4*)(Ws + (size_t)d * H + k0);
      const float4* wr4 = (const float4*)(Wr + (size_t)d * H + k0);
      const float4* wh4 = (const float4*)(Wh + (size_t)d * H + k0);
#pragma unroll
      for (int q = 0; q < 4; ++q) {
        float4 a = ws4[q], bq = wr4[q], cq = wh4[q];
        wsReg[4 * q + 0] = a.x; wsReg[4 * q + 1] = a.y;
        wsReg[4 * q + 2] = a.z; wsReg[4 * q + 3] = a.w;
        wrReg[4 * q + 0] = bq.x; wrReg[4 * q + 1] = bq.y;
        wrReg[4 * q + 2] = bq.z; wrReg[4 * q + 3] = bq.w;
        whReg[4 * q + 0] = cq.x; whReg[4 * q + 1] = cq.y;
        whReg[4 * q + 2] = cq.z; whReg[4 * q + 3] = cq.w;
      }
    }
    float biasReg = 0.0f, whbReg = 0.0f;
    float4 wt4Reg = {0.0f, 0.0f, 0.0f, 0.0f};
    float zpre = 0.0f;
    int zs = -1;
    if (t < 256) {
      int dd = t & (H - 1);
      biasReg = Ws_b[dd] + Wr_b[dd] + Wt_b[dd];
      whbReg = Wh_b[dd];
      wt4Reg = ((const float4*)Wt_w)[dd];
      int rr = t >> 7;
      zs = zsrc_[2 * b + rr];
      if (zs < 0) {
        int nd = rr ? v_[b] : u_[b];
        zpre = z0[(size_t)nd * H + dd];
      }
    }
    float omA = 0.0f, omB = 0.0f;
    if (t >= 256 && t < 768) {
      int w = (t - 256) >> 6;
      int lane = t & 63;
      int which = w & 3;
      int wsel = which >> 1;
      int offo = (which & 1) * H;
      float a0v = om0_w[offo + lane], a1v = om1_w[offo + lane];
      float b0v = om0_w[offo + 64 + lane], b1v = om1_w[offo + 64 + lane];
      omA = wsel ? a1v : a0v;
      omB = wsel ? b1v : b0v;
    }
    __syncthreads();  // staging visible

    // ---- B0: dependency-free gather (base whall versions) ----
    float mx = -INFINITY;
    for (int i = sub; i < c; i += 4) {
      int off = woffS[r][i];
      if (off < (int)OFF_WHALLV)
        mx = fmaxf(mx, nqS[r][i] * iq * wsf[(size_t)off + d]);
    }
    // ---- poll producers (t0), overlapped with B0 ----
    if (t == 0) {
      for (int w = 0; w < 4; ++w) {
        unsigned nw = need[b * 4 + w];
        if (!nw) continue;
        while ((__hip_atomic_load(&done[w], __ATOMIC_RELAXED,
                                  __HIP_MEMORY_SCOPE_AGENT) &
                nw) != nw)
          __builtin_amdgcn_s_sleep(1);
      }
      __threadfence();  // acquire
    }
    __syncthreads();

    const int ub = uvS[0], vb = uvS[1];

    // ---- B1: versioned gather + versioned z rows ----
    for (int i = sub; i < c; i += 4) {
      int off = woffS[r][i];
      if (off >= (int)OFF_WHALLV)
        mx = fmaxf(mx, nqS[r][i] * iq * wsf[(size_t)off + d]);
    }
    scratch[sub][r][d] = mx;
    if (t < 256) {
      int rr = t >> 7, dd = t & (H - 1);
      zrowS[rr][dd] = (zs < 0) ? zpre : wsf[OFF_ZVER + (size_t)zs * H + dd];
    }
    __syncthreads();

    // ---- C: combine -> hs ----
    if (t < 2 * H) {
      int rr = t >> 7, dd = t & (H - 1);
      float m = fmaxf(fmaxf(scratch[0][rr][dd], scratch[1][rr][dd]),
                      fmaxf(scratch[2][rr][dd], scratch[3][rr][dd]));
      hsS[rr][dd] = (cntS[rr] > 0) ? (1.0f / (1.0f + expf(-m))) : 0.0f;
    }
    __syncthreads();

    // ---- D: hpart = hs@Ws.T + zrow@Wr.T (registers) ----
    {
      float a0 = 0.0f, a1 = 0.0f;
#pragma unroll
      for (int kk = 0; kk < 16; ++kk) {
        int k = k0 + kk;
        a0 += hsS[0][k] * wsReg[kk] + zrowS[0][k] * wrReg[kk];
        a1 += hsS[1][k] * wsReg[kk] + zrowS[1][k] * wrReg[kk];
      }
      scratch[ks][0][d] = a0;
      scratch[ks][1][d] = a1;
    }
    __syncthreads();

    // ---- E: z_upd = sigmoid(h); write versioned z rows ----
    if (t < 2 * H) {
      int rr = t >> 7, dd = t & (H - 1);
      float acc = biasReg;
#pragma unroll
      for (int kx = 0; kx < 8; ++kx) acc += scratch[kx][rr][dd];
      acc += td2S[rr][0] * wt4Reg.x + td2S[rr][1] * wt4Reg.y +
             td2S[rr][2] * wt4Reg.z + td2S[rr][3] * wt4Reg.w;
      float zu = 1.0f / (1.0f + expf(-acc));
      zupdS[rr][dd] = zu;
      zver[(size_t)(2 * b + rr) * H + dd] = zu;
    }
    __syncthreads();

    // ---- F: hpart for whall rows u,v from NEW z rows (registers) ----
    {
      int r0 = (ub == vb) ? 1 : 0;  // final z[u] is zupd[1] when u==v
      float f0 = 0.0f, f1 = 0.0f;
#pragma unroll
      for (int kk = 0; kk < 16; ++kk) {
        int k = k0 + kk;
        f0 += zupdS[r0][k] * whReg[kk];
        f1 += zupdS[1][k] * whReg[kk];
      }
      scratch[ks][0][d] = f0;
      scratch[ks][1][d] = f1;
    }
    __syncthreads();

    // ---- G: whallv store (t<256) || dlog wave-reductions ([256,768)) ----
    if (t < 2 * H) {
      int rr = t >> 7, dd = t & (H - 1);
      float acc = whbReg;
#pragma unroll
      for (int kx = 0; kx < 8; ++kx) acc += scratch[kx][rr][dd];
      whallv[(size_t)(2 * b + rr) * H + dd] = acc;
    } else if (t < 768) {
      int w = (t - 256) >> 6;  // 8 waves: (row, which)
      int lane = t & 63;
      int row = w >> 2;
      int which = w & 3;  // 0:dL0 1:dR0 2:dL1 3:dR1
      int rr = (row == 0 && ub == vb) ? 1 : row;
      float val = zupdS[rr][lane] * omA + zupdS[rr][64 + lane] * omB;
      for (int s = 32; s > 0; s >>= 1) val += __shfl_down(val, s);
      if (lane == 0) dlog[b * 8 + which * 2 + row] = val;
    }
    __syncthreads();

    if (t == 0) {
      __threadfence();
      atomicOr(&done[b >> 5], 1u << (b & 31));
    }
    return;
  }

  // ================================ LAM ==================================
  const int b = blk - BB;
  const int e = et_[b];
  const int ub = u_[b], vb = v_[b];
  const float ps = psi[e], al = alpha[e], wt = w_t[e];
  const float ob0 = om0_b[0], ob1 = om1_b[0];
  const float ob = e ? ob1 : ob0;
  const float tcur = tt[b];
  const float inv_ps = 1.0f / (ps + 1e-7f);
  const int whichR = 2 * e + 1;  // dR_e
  const int whichL = 2 * e;      // dL_e

  if (t < BB) {
    uS[t] = u_[t];
    vS[t] = v_[t];
  }
  {
    const float4* base = (const float4*)(dvec0 + (size_t)whichR * N);
    float4* dst = (float4*)dR;
    for (int i = t; i < N / 4; i += 1024) dst[i] = base[i];
  }
  // poll all done bits for steps < b (overlapped with staging above)
  if (t == 0) {
    for (int w = 0; w < 4; ++w) {
      int cb = b - 32 * w;
      unsigned nw =
          (cb >= 32) ? 0xffffffffu : (cb <= 0 ? 0u : ((1u << cb) - 1u));
      if (!nw) continue;
      while ((__hip_atomic_load(&done[w], __ATOMIC_RELAXED,
                                __HIP_MEMORY_SCOPE_AGENT) &
              nw) != nw)
        __builtin_amdgcn_s_sleep(1);
    }
    __threadfence();  // acquire
  }
  __syncthreads();

  // apply log updates (steps < b), last-writer filtered so writes are unique
  for (int i = t; i < b; i += 1024) {
    int ui = uS[i], vi = vS[i];
    bool u_over = (ui == vi);
    bool v_over = false;
    for (int j = i + 1; j < b; ++j) {
      int uj = uS[j], vj = vS[j];
      u_over = u_over || (uj == ui) || (vj == ui);
      v_over = v_over || (uj == vi) || (vj == vi);
    }
    if (!u_over) dR[ui] = dlog[i * 8 + whichR * 2 + 0];
    if (!v_over) dR[vi] = dlog[i * 8 + whichR * 2 + 1];
  }

  if (t < 13) {
    auto dpre = [&](int x, int which) -> float {
      for (int bp = b - 1; bp >= 0; --bp) {
        if (vS[bp] == x) return dlog[bp * 8 + which * 2 + 1];
        if (uS[bp] == x) return dlog[bp * 8 + which * 2 + 0];
      }
      return dvec0[(size_t)which * N + x];
    };
    if (t < 11) {
      int li, ri;
      float ltu, ltv;
      if (t == 0) {
        li = ub; ri = vb;
        ltu = t_bar[(size_t)b * N + ub];
        ltv = t_bar[(size_t)b * N + vb];
      } else if (t <= 5) {
        int vn = neg_[b * (2 * KK) + (t - 1)];
        li = ub; ri = vn;
        ltu = t_bar[(size_t)b * N + ub];
        ltv = t_bar[(size_t)b * N + vn];
      } else {
        int un = neg_[b * (2 * KK) + (t - 1)];
        li = un; ri = vb;
        ltu = t_bar[(size_t)b * N + un];
        ltv = t_bar[(size_t)b * N + vb];
      }
      float g = dpre(li, whichL) + dpre(ri, whichR) + ob;
      float gp = fminf(fmaxf(g * inv_ps, -75.0f), 75.0f);
      float ts = tcur - fmaxf(ltu, ltv);
      out[b * 12 + t] = ps * log1pf(expf(gp)) + al * expf(-wt * (ts / TD_MAXF));
    } else if (t == 11) {
      suS = dpre(ub, whichL);
    } else {
      svS = dpre(vb, whichL);
    }
  }
  __syncthreads();

  const float su = suS, sv = svS;
  const float tb_u = t_bar[(size_t)b * N + ub];
  const float tb_v = t_bar[(size_t)b * N + vb];
  // factorizations: exp(g*ip) = K*exp(d*ip)  (clamp never triggers: |g|<=~16);
  // exp(-wt*(tcur-max(a,b))/TD) = C*max(exp(wt*a/TD), exp(wt*b/TD)), wt>0.
  const float Ku = expf((su + ob) * inv_ps);
  const float Kv = expf((sv + ob) * inv_ps);
  const float Cx = al * expf(-wt * (tcur / TD_MAXF));
  const float Eu = expf(wt * (tb_u / TD_MAXF));
  const float Ev = expf(wt * (tb_v / TD_MAXF));
  const float wTD = wt / TD_MAXF;
  const float4* tb4 = (const float4*)(t_bar + (size_t)b * N);
  const float4* dR4 = (const float4*)dR;
  float acc = 0.0f;
  for (int j4 = t; j4 < N / 4; j4 += 1024) {
    float4 dv = dR4[j4];
    float4 tb = tb4[j4];
    float de[4] = {dv.x, dv.y, dv.z, dv.w};
    float te[4] = {tb.x, tb.y, tb.z, tb.w};
#pragma unroll
    for (int ee = 0; ee < 4; ++ee) {
      int j = j4 * 4 + ee;
      if (j == ub || j == vb) continue;
      float Dj = expf(de[ee] * inv_ps);
      float spl = ps * (log1pf(Ku * Dj) + log1pf(Kv * Dj));
      float Ej = expf(wTD * te[ee]);
      float ex = Cx * (fmaxf(Eu, Ej) + fmaxf(Ev, Ej));
      acc += spl + ex;
    }
  }
  red[t] = acc;
  __syncthreads();
  for (int s = 512; s > 0; s >>= 1) {
    if (t < s) red[t] += red[t + s];
    __syncthreads();
  }
  if (t == 0) out[b * 12 + 11] = red[0];
}

// ---------------------------------------------------------------------------
extern "C" void kernel_launch(void* const* d_in, const int* in_sizes, int n_in,
                              void* d_out, int out_size, void* d_ws,
                              size_t ws_size, hipStream_t stream) {
  const int* u = (const int*)d_in[0];
  const int* v = (const int*)d_in[1];
  const int* et = (const int*)d_in[2];
  const int* neg = (const int*)d_in[3];
  const float* time_diff = (const float*)d_in[4];
  const float* t_bar = (const float*)d_in[5];
  const float* t = (const float*)d_in[6];
  const float* z0 = (const float*)d_in[7];
  const float* A = (const float*)d_in[8];
  const float* S = (const float*)d_in[9];
  const float* w_t = (const float*)d_in[10];
  const float* alpha = (const float*)d_in[11];
  const float* psi = (const float*)d_in[12];
  const float* om0_w = (const float*)d_in[13];
  const float* om0_b = (const float*)d_in[14];
  const float* om1_w = (const float*)d_in[15];
  const float* om1_b = (const float*)d_in[16];
  const float* Wh_w = (const float*)d_in[17];
  const float* Wh_b = (const float*)d_in[18];
  const float* Ws_w = (const float*)d_in[19];
  const float* Ws_b = (const float*)d_in[20];
  const float* Wr_w = (const float*)d_in[21];
  const float* Wr_b = (const float*)d_in[22];
  const float* Wt_w = (const float*)d_in[23];
  const float* Wt_b = (const float*)d_in[24];
  float* out = (float*)d_out;

  float* wsf = (float*)d_ws;
  float* whall = wsf;                           // N*H (offset 0)
  float* whallv = wsf + OFF_WHALLV;             // 2*BB*H
  float* zver = wsf + OFF_ZVER;                 // 2*BB*H
  float* dvec0 = zver + 2 * BB * H;             // 4*N
  float* dlog = dvec0 + 4 * N;                  // 8*BB
  float* qsum = dlog + 8 * BB;                  // 2*BB
  int* cnt = (int*)(qsum + 2 * BB);             // 2*BB
  int* nidx = cnt + 2 * BB;                     // 2*BB*MAXN
  float* nes = (float*)(nidx + 2 * BB * MAXN);  // 2*BB*MAXN
  int* woff = (int*)(nes + 2 * BB * MAXN);      // 2*BB*MAXN
  int* zsrc = woff + 2 * BB * MAXN;             // 2*BB
  unsigned* need = (unsigned*)(zsrc + 2 * BB);  // 4*BB
  unsigned* done = need + 4 * BB;               // 4 (contiguous after need)

  hipMemsetAsync(need, 0, (4 * BB + 4) * sizeof(unsigned), stream);
  build_kernel<<<N / 2 + 2 * BB + N / 256, 256, 0, stream>>>(
      z0, Wh_w, Wh_b, whall, u, v, A, S, om0_w, om1_w, dvec0, cnt, nidx, nes,
      qsum, woff, zsrc, need);
  fused_kernel<<<2 * BB, 1024, 0, stream>>>(
      u, v, et, neg, time_diff, t_bar, t, z0, Wh_w, Ws_w, Wr_w, om0_w, om1_w,
      Wh_b, Ws_b, Wr_b, Wt_w, Wt_b, w_t, alpha, psi, om0_b, om1_b, wsf, zver,
      whallv, dlog, qsum, cnt, nes, woff, zsrc, dvec0, need, done, out);
}

// Round 8
// 601.594 us; speedup vs baseline: 1.0627x; 1.0627x over previous
//
#include <hip/hip_runtime.h>
#include <math.h>

#define N 8192
#define H 128
#define BB 100
#define KK 5
#define MAXN 256
#define TD_MAXF 10000.0f

// ws float-offset layout constants (single-base addressing for the gather)
#define OFF_WHALLV ((size_t)N * H)          // versioned whall rows
#define OFF_ZVER (OFF_WHALLV + 2 * BB * H)  // versioned z rows

// ---------------------------------------------------------------------------
// K1: weights transpose + omega pack + flag zero + dbase, by idx range.
__global__ __launch_bounds__(256) void prep_all_kernel(
    const float* __restrict__ Wh, const float* __restrict__ Ws,
    const float* __restrict__ Wr, const float* __restrict__ om0,
    const float* __restrict__ om1, const float* __restrict__ z0,
    float* __restrict__ WhT, float* __restrict__ WsT, float* __restrict__ WrT,
    float* __restrict__ omP, unsigned* __restrict__ flags,
    float* __restrict__ dvec0) {
  const int B0 = H * H, B1 = 2 * H * H, B2 = 3 * H * H;
  const int B3 = B2 + 2 * H, B4 = B2 + 4 * H, B5 = B4 + 4 * BB + 4;
  int idx = blockIdx.x * 256 + threadIdx.x;
  if (idx < B0) {
    int d = idx >> 7, k = idx & (H - 1);
    WhT[k * H + d] = Wh[d * H + k];
  } else if (idx < B1) {
    int e = idx - B0;
    int d = e >> 7, k = e & (H - 1);
    WsT[k * H + d] = Ws[d * H + k];
  } else if (idx < B2) {
    int e = idx - B1;
    int d = e >> 7, k = e & (H - 1);
    WrT[k * H + d] = Wr[d * H + k];
  } else if (idx < B3) {
    int e = idx - B2;
    omP[e] = om0[e];
  } else if (idx < B4) {
    int e = idx - B3;
    omP[2 * H + e] = om1[e];
  } else if (idx < B5) {
    flags[idx - B4] = 0u;  // need[4*BB] then done[4]
  } else if (idx < B5 + N) {
    int j = idx - B5;
    const float4* zr = (const float4*)(z0 + (size_t)j * H);
    const float4* o0 = (const float4*)om0;
    const float4* o1 = (const float4*)om1;
    float a0 = 0, b0 = 0, a1 = 0, b1 = 0;
    for (int k = 0; k < H / 4; ++k) {
      float4 zv = zr[k];
      float4 l0 = o0[k], r0 = o0[k + H / 4];
      float4 l1 = o1[k], r1 = o1[k + H / 4];
      a0 += zv.x * l0.x + zv.y * l0.y + zv.z * l0.z + zv.w * l0.w;
      b0 += zv.x * r0.x + zv.y * r0.y + zv.z * r0.z + zv.w * r0.w;
      a1 += zv.x * l1.x + zv.y * l1.y + zv.z * l1.z + zv.w * l1.w;
      b1 += zv.x * r1.x + zv.y * r1.y + zv.z * r1.z + zv.w * r1.w;
    }
    dvec0[0 * N + j] = a0;
    dvec0[1 * N + j] = b0;
    dvec0[2 * N + j] = a1;
    dvec0[3 * N + j] = b1;
  }
}

// ---------------------------------------------------------------------------
// K2: fused by block range. Blocks [0, N/2): whall (2 rows per block).
// Blocks [N/2, N/2 + 2*BB): nbr list build + DAG resolve for list l.
__global__ __launch_bounds__(256) void build_kernel(
    const float* __restrict__ z0, const float* __restrict__ WhT,
    const float* __restrict__ Wh_b, float* __restrict__ whall,
    const int* __restrict__ u_, const int* __restrict__ v_,
    const float* __restrict__ A, const float* __restrict__ S,
    int* __restrict__ cnt, int* __restrict__ nidx, float* __restrict__ nes,
    float* __restrict__ qsum, int* __restrict__ woff, int* __restrict__ zsrc,
    unsigned* __restrict__ need) {
  const int blk = blockIdx.x;
  const int tid = threadIdx.x;
  __shared__ float zr2[2][H];
  __shared__ int cnts[256];
  __shared__ int excl[257];
  __shared__ float ssum[256];
  __shared__ int nidxL[MAXN];
  __shared__ int uL[BB], vL[BB];

  if (blk < N / 2) {
    int r = tid >> 7, d = tid & (H - 1);
    int row = blk * 2 + r;
    zr2[r][d] = z0[(size_t)row * H + d];
    __syncthreads();
    float acc = Wh_b[d];
#pragma unroll 8
    for (int k = 0; k < H; ++k) acc += zr2[r][k] * WhT[k * H + d];
    whall[(size_t)row * H + d] = acc;
    return;
  }

  const int l = blk - N / 2;
  const int b = l >> 1, r = l & 1;
  const int node = r ? u_[b] : v_[b];
  int c = 0;
  float local = 0.0f;
  unsigned hitmask = 0u;  // single-pass A: remember hits per iteration
  for (int it = 0; it < N / 256; ++it) {
    int j = it * 256 + tid;
    if (A[(size_t)node * N + j] > 0.0f) {
      hitmask |= (1u << it);
      ++c;
      local += expf(S[(size_t)node * N + j]);
    }
  }
  cnts[tid] = c;
  ssum[tid] = local;
  __syncthreads();
  if (tid == 0) {
    int s = 0;
    for (int i = 0; i < 256; ++i) { excl[i] = s; s += cnts[i]; }
    excl[256] = s;
  }
  __syncthreads();
  int p = excl[tid];
  for (int it = 0; it < N / 256; ++it) {
    if ((hitmask >> it) & 1u) {
      int j = it * 256 + tid;
      if (p < MAXN) {
        nidx[l * MAXN + p] = j;
        nidxL[p] = j;
        nes[l * MAXN + p] = expf(S[(size_t)node * N + j]);
      }
      ++p;
    }
  }
  if (tid < BB) {
    uL[tid] = u_[tid];
    vL[tid] = v_[tid];
  }
  __syncthreads();
  for (int s = 128; s > 0; s >>= 1) {
    if (tid < s) ssum[tid] += ssum[tid + s];
    __syncthreads();
  }
  const int cM = min(excl[256], MAXN);
  if (tid == 0) {
    cnt[l] = cM;
    qsum[l] = ssum[0];
  }
  for (int i = tid; i < cM; i += 256) {
    int n = nidxL[i];
    int a = -1, row = 0;
    for (int s = b - 1; s >= 0; --s) {
      if (vL[s] == n) { a = s; row = 1; break; }
      if (uL[s] == n) { a = s; row = 0; break; }
    }
    int off;
    if (a < 0) {
      off = n * H;
    } else {
      off = (int)OFF_WHALLV + (2 * a + row) * H;
      atomicOr(&need[b * 4 + (a >> 5)], 1u << (a & 31));
    }
    woff[l * MAXN + i] = off;
  }
  if (r == 0 && tid >= 254) {
    int which = tid - 254;  // 0 -> u_b, 1 -> v_b
    int nd = which ? vL[b] : uL[b];
    int a = -1, row = 0;
    for (int s = b - 1; s >= 0; --s) {
      if (vL[s] == nd) { a = s; row = 1; break; }
      if (uL[s] == nd) { a = s; row = 0; break; }
    }
    int sv = -1;
    if (a >= 0) {
      sv = 2 * a + row;
      atomicOr(&need[b * 4 + (a >> 5)], 1u << (a & 31));
    }
    zsrc[2 * b + which] = sv;
  }
}

// ---------------------------------------------------------------------------
// K3 fused: blocks [0,BB) = DAG-parallel step; blocks [BB,2BB) = lam for
// step blk-BB (polls the same done bits; needs only steps < b).
__global__ __launch_bounds__(1024) void fused_kernel(
    const int* __restrict__ u_, const int* __restrict__ v_,
    const int* __restrict__ et_, const int* __restrict__ neg_,
    const float* __restrict__ time_diff, const float* __restrict__ t_bar,
    const float* __restrict__ tt, const float* __restrict__ z0,
    const float* __restrict__ WhT, const float* __restrict__ WsT,
    const float* __restrict__ WrT, const float* __restrict__ omP,
    const float* __restrict__ Wh_b, const float* __restrict__ Ws_b,
    const float* __restrict__ Wr_b, const float* __restrict__ Wt_w,
    const float* __restrict__ Wt_b, const float* __restrict__ w_t,
    const float* __restrict__ alpha, const float* __restrict__ psi,
    const float* __restrict__ om0_b, const float* __restrict__ om1_b,
    const float* __restrict__ wsf, float* __restrict__ zver,
    float* __restrict__ whallv, float* __restrict__ dlog,
    const float* __restrict__ qsum_, const int* __restrict__ cnt_,
    const float* __restrict__ nes_, const int* __restrict__ woff_,
    const int* __restrict__ zsrc_, const float* __restrict__ dvec0,
    const unsigned* __restrict__ need, unsigned* done,
    float* __restrict__ out) {
  const int blk = blockIdx.x;
  const int t = threadIdx.x;
  // step-part LDS
  __shared__ float scratch[8][2][H];
  __shared__ float hsS[2][H];
  __shared__ float zrowS[2][H];
  __shared__ float zupdS[2][H];
  __shared__ float td2S[2][4];
  __shared__ int woffS[2][MAXN];
  __shared__ float nqS[2][MAXN];
  __shared__ int cntS[2];
  __shared__ int uvS[2];
  // lam-part LDS
  __shared__ float dR[N];  // 32 KB
  __shared__ int uS[BB], vS[BB];
  __shared__ float red[1024];
  __shared__ float suS, svS;

  if (blk < BB) {
    // =============================== STEP ================================
    const int b = blk;
    const int r = t >> 9;
    const int sub = (t >> 7) & 3;
    const int d = t & (H - 1);
    const int l = 2 * b + r;
    const int c = cnt_[l];
    const float iq = 1.0f / (qsum_[l] + 1e-7f);
    const int ks = t >> 7;
    const int k0 = ks * 16;

    // ---- pre-poll staging (LDS) ----
    if (t < 512) {
      int rr = t >> 8, i = t & 255;
      woffS[rr][i] = woff_[(2 * b + rr) * MAXN + i];
      nqS[rr][i] = nes_[(2 * b + rr) * MAXN + i];
    } else if (t < 520) {
      int i = t - 512;
      int cc = i & 3;
      float sd = (cc == 0) ? 50.0f : ((cc == 1) ? 7.0f : 15.0f);
      td2S[i >> 2][cc] = time_diff[b * 8 + i] / sd;
    } else if (t < 522) {
      cntS[t - 520] = cnt_[2 * b + (t - 520)];
    } else if (t == 522) {
      uvS[0] = u_[b];
    } else if (t == 523) {
      uvS[1] = v_[b];
    }
    // ---- pre-poll register prefetch (coalesced transposed weights) ----
    float wsReg[16], wrReg[16], whReg[16];
#pragma unroll
    for (int kk = 0; kk < 16; ++kk) {
      wsReg[kk] = WsT[(k0 + kk) * H + d];
      wrReg[kk] = WrT[(k0 + kk) * H + d];
      whReg[kk] = WhT[(k0 + kk) * H + d];
    }
    float biasReg = 0.0f, whbReg = 0.0f;
    float4 wt4Reg = {0.0f, 0.0f, 0.0f, 0.0f};
    float zpre = 0.0f;
    int zs = -1;
    if (t < 256) {
      int dd = t & (H - 1);
      biasReg = Ws_b[dd] + Wr_b[dd] + Wt_b[dd];
      whbReg = Wh_b[dd];
      wt4Reg = ((const float4*)Wt_w)[dd];
      int rr = t >> 7;
      zs = zsrc_[2 * b + rr];
      if (zs < 0) {
        int nd = rr ? v_[b] : u_[b];
        zpre = z0[(size_t)nd * H + dd];
      }
    }
    float omA = 0.0f, omB = 0.0f;
    if (t >= 256 && t < 768) {
      int w = (t - 256) >> 6;
      int lane = t & 63;
      int which = w & 3;
      int wsel = which >> 1;
      int offo = (which & 1) * H;
      omA = omP[wsel * 2 * H + offo + lane];
      omB = omP[wsel * 2 * H + offo + 64 + lane];
    }
    __syncthreads();  // staging visible

    // ---- B0: dependency-free gather (base whall versions) ----
    float mx = -INFINITY;
    for (int i = sub; i < c; i += 4) {
      int off = woffS[r][i];
      if (off < (int)OFF_WHALLV)
        mx = fmaxf(mx, nqS[r][i] * iq * wsf[(size_t)off + d]);
    }
    // ---- poll producers (t0), overlapped with B0 ----
    if (t == 0) {
      for (int w = 0; w < 4; ++w) {
        unsigned nw = need[b * 4 + w];
        if (!nw) continue;
        while ((__hip_atomic_load(&done[w], __ATOMIC_RELAXED,
                                  __HIP_MEMORY_SCOPE_AGENT) &
                nw) != nw)
          __builtin_amdgcn_s_sleep(1);
      }
      __threadfence();  // acquire
    }
    __syncthreads();

    const int ub = uvS[0], vb = uvS[1];

    // ---- B1: versioned gather + versioned z rows ----
    for (int i = sub; i < c; i += 4) {
      int off = woffS[r][i];
      if (off >= (int)OFF_WHALLV)
        mx = fmaxf(mx, nqS[r][i] * iq * wsf[(size_t)off + d]);
    }
    scratch[sub][r][d] = mx;
    if (t < 256) {
      int rr = t >> 7, dd = t & (H - 1);
      zrowS[rr][dd] = (zs < 0) ? zpre : wsf[OFF_ZVER + (size_t)zs * H + dd];
    }
    __syncthreads();

    // ---- C: combine -> hs ----
    if (t < 2 * H) {
      int rr = t >> 7, dd = t & (H - 1);
      float m = fmaxf(fmaxf(scratch[0][rr][dd], scratch[1][rr][dd]),
                      fmaxf(scratch[2][rr][dd], scratch[3][rr][dd]));
      hsS[rr][dd] = (cntS[rr] > 0) ? (1.0f / (1.0f + expf(-m))) : 0.0f;
    }
    __syncthreads();

    // ---- D: hpart = hs@Ws.T + zrow@Wr.T (registers) ----
    {
      float a0 = 0.0f, a1 = 0.0f;
#pragma unroll
      for (int kk = 0; kk < 16; ++kk) {
        int k = k0 + kk;
        a0 += hsS[0][k] * wsReg[kk] + zrowS[0][k] * wrReg[kk];
        a1 += hsS[1][k] * wsReg[kk] + zrowS[1][k] * wrReg[kk];
      }
      scratch[ks][0][d] = a0;
      scratch[ks][1][d] = a1;
    }
    __syncthreads();

    // ---- E: z_upd = sigmoid(h); write versioned z rows ----
    if (t < 2 * H) {
      int rr = t >> 7, dd = t & (H - 1);
      float acc = biasReg;
#pragma unroll
      for (int kx = 0; kx < 8; ++kx) acc += scratch[kx][rr][dd];
      acc += td2S[rr][0] * wt4Reg.x + td2S[rr][1] * wt4Reg.y +
             td2S[rr][2] * wt4Reg.z + td2S[rr][3] * wt4Reg.w;
      float zu = 1.0f / (1.0f + expf(-acc));
      zupdS[rr][dd] = zu;
      zver[(size_t)(2 * b + rr) * H + dd] = zu;
    }
    __syncthreads();

    // ---- F: hpart for whall rows u,v from NEW z rows (registers) ----
    {
      int r0 = (ub == vb) ? 1 : 0;  // final z[u] is zupd[1] when u==v
      float f0 = 0.0f, f1 = 0.0f;
#pragma unroll
      for (int kk = 0; kk < 16; ++kk) {
        int k = k0 + kk;
        f0 += zupdS[r0][k] * whReg[kk];
        f1 += zupdS[1][k] * whReg[kk];
      }
      scratch[ks][0][d] = f0;
      scratch[ks][1][d] = f1;
    }
    __syncthreads();

    // ---- G: whallv store (t<256) || dlog wave-reductions ([256,768)) ----
    if (t < 2 * H) {
      int rr = t >> 7, dd = t & (H - 1);
      float acc = whbReg;
#pragma unroll
      for (int kx = 0; kx < 8; ++kx) acc += scratch[kx][rr][dd];
      whallv[(size_t)(2 * b + rr) * H + dd] = acc;
    } else if (t < 768) {
      int w = (t - 256) >> 6;  // 8 waves: (row, which)
      int lane = t & 63;
      int row = w >> 2;
      int which = w & 3;  // 0:dL0 1:dR0 2:dL1 3:dR1
      int rr = (row == 0 && ub == vb) ? 1 : row;
      float val = zupdS[rr][lane] * omA + zupdS[rr][64 + lane] * omB;
      for (int s = 32; s > 0; s >>= 1) val += __shfl_down(val, s);
      if (lane == 0) dlog[b * 8 + which * 2 + row] = val;
    }
    __syncthreads();

    if (t == 0) {
      __threadfence();
      atomicOr(&done[b >> 5], 1u << (b & 31));
    }
    return;
  }

  // ================================ LAM ==================================
  const int b = blk - BB;
  const int e = et_[b];
  const int ub = u_[b], vb = v_[b];
  const float ps = psi[e], al = alpha[e], wt = w_t[e];
  const float ob0 = om0_b[0], ob1 = om1_b[0];
  const float ob = e ? ob1 : ob0;
  const float tcur = tt[b];
  const float inv_ps = 1.0f / (ps + 1e-7f);
  const int whichR = 2 * e + 1;  // dR_e
  const int whichL = 2 * e;      // dL_e

  if (t < BB) {
    uS[t] = u_[t];
    vS[t] = v_[t];
  }
  {
    const float4* base = (const float4*)(dvec0 + (size_t)whichR * N);
    float4* dst = (float4*)dR;
    for (int i = t; i < N / 4; i += 1024) dst[i] = base[i];
  }
  // poll all done bits for steps < b (overlapped with staging above)
  if (t == 0) {
    for (int w = 0; w < 4; ++w) {
      int cb = b - 32 * w;
      unsigned nw =
          (cb >= 32) ? 0xffffffffu : (cb <= 0 ? 0u : ((1u << cb) - 1u));
      if (!nw) continue;
      while ((__hip_atomic_load(&done[w], __ATOMIC_RELAXED,
                                __HIP_MEMORY_SCOPE_AGENT) &
              nw) != nw)
        __builtin_amdgcn_s_sleep(1);
    }
    __threadfence();  // acquire
  }
  __syncthreads();

  // apply log updates (steps < b), last-writer filtered so writes are unique
  for (int i = t; i < b; i += 1024) {
    int ui = uS[i], vi = vS[i];
    bool u_over = (ui == vi);
    bool v_over = false;
    for (int j = i + 1; j < b; ++j) {
      int uj = uS[j], vj = vS[j];
      u_over = u_over || (uj == ui) || (vj == ui);
      v_over = v_over || (uj == vi) || (vj == vi);
    }
    if (!u_over) dR[ui] = dlog[i * 8 + whichR * 2 + 0];
    if (!v_over) dR[vi] = dlog[i * 8 + whichR * 2 + 1];
  }

  if (t < 13) {
    auto dpre = [&](int x, int which) -> float {
      for (int bp = b - 1; bp >= 0; --bp) {
        if (vS[bp] == x) return dlog[bp * 8 + which * 2 + 1];
        if (uS[bp] == x) return dlog[bp * 8 + which * 2 + 0];
      }
      return dvec0[(size_t)which * N + x];
    };
    if (t < 11) {
      int li, ri;
      float ltu, ltv;
      if (t == 0) {
        li = ub; ri = vb;
        ltu = t_bar[(size_t)b * N + ub];
        ltv = t_bar[(size_t)b * N + vb];
      } else if (t <= 5) {
        int vn = neg_[b * (2 * KK) + (t - 1)];
        li = ub; ri = vn;
        ltu = t_bar[(size_t)b * N + ub];
        ltv = t_bar[(size_t)b * N + vn];
      } else {
        int un = neg_[b * (2 * KK) + (t - 1)];
        li = un; ri = vb;
        ltu = t_bar[(size_t)b * N + un];
        ltv = t_bar[(size_t)b * N + vb];
      }
      float g = dpre(li, whichL) + dpre(ri, whichR) + ob;
      float gp = fminf(fmaxf(g * inv_ps, -75.0f), 75.0f);
      float ts = tcur - fmaxf(ltu, ltv);
      out[b * 12 + t] = ps * log1pf(expf(gp)) + al * expf(-wt * (ts / TD_MAXF));
    } else if (t == 11) {
      suS = dpre(ub, whichL);
    } else {
      svS = dpre(vb, whichL);
    }
  }
  __syncthreads();

  const float su = suS, sv = svS;
  const float tb_u = t_bar[(size_t)b * N + ub];
  const float tb_v = t_bar[(size_t)b * N + vb];
  // factorizations: exp(g*ip) = K*exp(d*ip)  (clamp never triggers: |g|<=~16);
  // exp(-wt*(tcur-max(a,b))/TD) = C*max(exp(wt*a/TD), exp(wt*b/TD)), wt>0.
  const float Ku = expf((su + ob) * inv_ps);
  const float Kv = expf((sv + ob) * inv_ps);
  const float Cx = al * expf(-wt * (tcur / TD_MAXF));
  const float Eu = expf(wt * (tb_u / TD_MAXF));
  const float Ev = expf(wt * (tb_v / TD_MAXF));
  const float wTD = wt / TD_MAXF;
  const float4* tb4 = (const float4*)(t_bar + (size_t)b * N);
  const float4* dR4 = (const float4*)dR;
  float acc = 0.0f;
  for (int j4 = t; j4 < N / 4; j4 += 1024) {
    float4 dv = dR4[j4];
    float4 tb = tb4[j4];
    float de[4] = {dv.x, dv.y, dv.z, dv.w};
    float te[4] = {tb.x, tb.y, tb.z, tb.w};
#pragma unroll
    for (int ee = 0; ee < 4; ++ee) {
      int j = j4 * 4 + ee;
      if (j == ub || j == vb) continue;
      float Dj = expf(de[ee] * inv_ps);
      float spl = ps * (log1pf(Ku * Dj) + log1pf(Kv * Dj));
      float Ej = expf(wTD * te[ee]);
      float ex = Cx * (fmaxf(Eu, Ej) + fmaxf(Ev, Ej));
      acc += spl + ex;
    }
  }
  red[t] = acc;
  __syncthreads();
  for (int s = 512; s > 0; s >>= 1) {
    if (t < s) red[t] += red[t + s];
    __syncthreads();
  }
  if (t == 0) out[b * 12 + 11] = red[0];
}

// ---------------------------------------------------------------------------
extern "C" void kernel_launch(void* const* d_in, const int* in_sizes, int n_in,
                              void* d_out, int out_size, void* d_ws,
                              size_t ws_size, hipStream_t stream) {
  const int* u = (const int*)d_in[0];
  const int* v = (const int*)d_in[1];
  const int* et = (const int*)d_in[2];
  const int* neg = (const int*)d_in[3];
  const float* time_diff = (const float*)d_in[4];
  const float* t_bar = (const float*)d_in[5];
  const float* t = (const float*)d_in[6];
  const float* z0 = (const float*)d_in[7];
  const float* A = (const float*)d_in[8];
  const float* S = (const float*)d_in[9];
  const float* w_t = (const float*)d_in[10];
  const float* alpha = (const float*)d_in[11];
  const float* psi = (const float*)d_in[12];
  const float* om0_w = (const float*)d_in[13];
  const float* om0_b = (const float*)d_in[14];
  const float* om1_w = (const float*)d_in[15];
  const float* om1_b = (const float*)d_in[16];
  const float* Wh_w = (const float*)d_in[17];
  const float* Wh_b = (const float*)d_in[18];
  const float* Ws_w = (const float*)d_in[19];
  const float* Ws_b = (const float*)d_in[20];
  const float* Wr_w = (const float*)d_in[21];
  const float* Wr_b = (const float*)d_in[22];
  const float* Wt_w = (const float*)d_in[23];
  const float* Wt_b = (const float*)d_in[24];
  float* out = (float*)d_out;

  float* wsf = (float*)d_ws;
  float* whall = wsf;                           // N*H (offset 0)
  float* whallv = wsf + OFF_WHALLV;             // 2*BB*H
  float* zver = wsf + OFF_ZVER;                 // 2*BB*H
  float* WhT = zver + 2 * BB * H;               // H*H
  float* WsT = WhT + H * H;                     // H*H
  float* WrT = WsT + H * H;                     // H*H
  float* omP = WrT + H * H;                     // 4*H
  float* dvec0 = omP + 4 * H;                   // 4*N
  float* dlog = dvec0 + 4 * N;                  // 8*BB
  float* qsum = dlog + 8 * BB;                  // 2*BB
  int* cnt = (int*)(qsum + 2 * BB);             // 2*BB
  int* nidx = cnt + 2 * BB;                     // 2*BB*MAXN
  float* nes = (float*)(nidx + 2 * BB * MAXN);  // 2*BB*MAXN
  int* woff = (int*)(nes + 2 * BB * MAXN);      // 2*BB*MAXN
  int* zsrc = woff + 2 * BB * MAXN;             // 2*BB
  unsigned* need = (unsigned*)(zsrc + 2 * BB);  // 4*BB
  unsigned* done = need + 4 * BB;               // 4 (contiguous after need)

  const int PREP_ELEMS = 3 * H * H + 4 * H + 4 * BB + 4 + N;
  prep_all_kernel<<<(PREP_ELEMS + 255) / 256, 256, 0, stream>>>(
      Wh_w, Ws_w, Wr_w, om0_w, om1_w, z0, WhT, WsT, WrT, omP, need, dvec0);
  build_kernel<<<N / 2 + 2 * BB, 256, 0, stream>>>(
      z0, WhT, Wh_b, whall, u, v, A, S, cnt, nidx, nes, qsum, woff, zsrc,
      need);
  fused_kernel<<<2 * BB, 1024, 0, stream>>>(
      u, v, et, neg, time_diff, t_bar, t, z0, WhT, WsT, WrT, omP, Wh_b, Ws_b,
      Wr_b, Wt_w, Wt_b, w_t, alpha, psi, om0_b, om1_b, wsf, zver, whallv,
      dlog, qsum, cnt, nes, woff, zsrc, dvec0, need, done, out);
}